// Round 7
// baseline (332.704 us; speedup 1.0000x reference)
//
#include <hip/hip_runtime.h>

#define B_ 64
#define N_ 8192

using short8 = __attribute__((ext_vector_type(8))) short;  // 8 bf16 (4 VGPRs)
using f32x4  = __attribute__((ext_vector_type(4))) float;

#define MFMA16(a, b, c) __builtin_amdgcn_mfma_f32_16x16x32_bf16((a), (b), (c), 0, 0, 0)

// round-half-up bf16: same 2^-9 max-rel-err bound as RNE, 2 VALU instrs
__device__ inline unsigned short f2bf(float f) {
  union { float f; unsigned int u; } v; v.f = f;
  return (unsigned short)((v.u + 0x8000u) >> 16);
}
__device__ inline float bf2f(unsigned int hi16_in_low) {
  union { unsigned int u; float f; } v; v.u = hi16_in_low << 16;
  return v.f;
}

// ws layout (f32 indices):
//   stats [0,1024) | cnt [1024,1088) | pmax [1088,66624)  (1024 blocks x 64)
//   ushort wb = (ushort*)(wsf+66624):
//     BM   [16 j][32]  @0     (M' = W_lq' W_rk'^T, kk 0..10 = M'[kk][j])
//     BL   [64 c][32]  @512   (kk 0..9 = W_l[kk][c], kk10 = b_l[c])
//     BRV2 [64 c][32]  @2560  (kk 0..12 = (W_r.W_v^T)[kk][c], kk13 = b_rv[c])
//     BT   [64 c][64]  @4608  (W_t)
//     tg   [B][N][64]  @8704  (t, bf16, b-major)
// A-tile k-slots: 0..9 = x, 10 = 1, 11..15 = 0, 16..28 = y, 29 = 1, 30,31 = 0.

// ---- k0: weight prep + zero stats/counters -------------------------------
__global__ void k0_prep(const float* __restrict__ W_l, const float* __restrict__ b_l,
                        const float* __restrict__ W_r, const float* __restrict__ b_r,
                        const float* __restrict__ W_qk, const float* __restrict__ W_v,
                        const float* __restrict__ b_v, const float* __restrict__ W_t,
                        float* __restrict__ wsf) {
  const int tid = threadIdx.x;
  unsigned short* wb   = (unsigned short*)(wsf + 66624);
  unsigned short* BM   = wb;
  unsigned short* BL   = wb + 512;
  unsigned short* BRV2 = wb + 2560;
  unsigned short* BT   = wb + 4608;
  if (blockIdx.x == 0) {
    __shared__ float Wlq[11 * 16], Wrk[14 * 16];
    for (int idx = tid; idx < 11 * 16; idx += 256) {
      int i = idx >> 4, d = idx & 15;
      const float* a = (i < 10) ? (W_l + i * 64) : b_l;
      float s = 0.f;
      for (int c = 0; c < 64; ++c) s = fmaf(a[c], W_qk[d * 64 + c], s);
      Wlq[idx] = s;
    }
    for (int idx = tid; idx < 14 * 16; idx += 256) {
      int j = idx >> 4, d = idx & 15;
      const float* a = (j < 13) ? (W_r + j * 64) : b_r;
      float s = 0.f;
      for (int c = 0; c < 64; ++c) s = fmaf(a[c], W_qk[d * 64 + c], s);
      Wrk[idx] = s;
    }
    __syncthreads();
    for (int idx = tid; idx < 512; idx += 256) {
      int j = idx >> 5, kk = idx & 31;
      unsigned short o = 0;
      if (j < 14 && kk < 11) {
        float s = 0.f;
        for (int d = 0; d < 16; ++d) s = fmaf(Wlq[kk * 16 + d], Wrk[j * 16 + d], s);
        o = f2bf(s);
      }
      BM[idx] = o;
    }
  } else if (blockIdx.x == 1) {
    for (int idx = tid; idx < 2048; idx += 256) {
      int c = idx >> 5, kk = idx & 31;
      unsigned short o = 0;
      if (kk < 13) {
        float s = 0.f;
        for (int j = 0; j < 64; ++j) s = fmaf(W_r[kk * 64 + j], W_v[c * 64 + j], s);
        o = f2bf(s);
      } else if (kk == 13) {
        float s = b_v[c];
        for (int j = 0; j < 64; ++j) s = fmaf(b_r[j], W_v[c * 64 + j], s);
        o = f2bf(s);
      }
      BRV2[idx] = o;
    }
  } else if (blockIdx.x == 2) {
    for (int idx = tid; idx < 2048; idx += 256) {
      int c = idx >> 5, kk = idx & 31;
      unsigned short o = 0;
      if (kk < 10) o = f2bf(W_l[kk * 64 + c]);
      else if (kk == 10) o = f2bf(b_l[c]);
      BL[idx] = o;
    }
    for (int i = tid; i < 1088; i += 256) wsf[i] = 0.f;   // stats + counters
  } else {
    for (int i = tid; i < 4096; i += 256) BT[i] = f2bf(W_t[i]);
  }
}

// ---- k1: fused per-point chain, 2 points/block, time-muxed wave tiles ----
__global__ __launch_bounds__(256, 5)
void k1_attn(const float* __restrict__ x, const float* __restrict__ y,
             const float* __restrict__ wsf, const float* __restrict__ b_t,
             float* __restrict__ stats) {
  // LDS: 13056 shorts (26112 B) + 1024 f32 (4096 B) = 30208 B -> 5 blocks/CU
  __shared__ __align__(16) short lds[13056];
  __shared__ float scr[1024];
  short* const Axy[2] = {lds, lds + 2560};          // [b][k-slot] per point
  short* const YTb[2] = {lds + 5120, lds + 6272};   // yhat^T [j][e] per point
  short* const awB    = lds + 7424;                 // per-wave [16][72], reused p0->p1
  short* const guB    = lds + 12032;                // per-wave [16][16], reused

  const unsigned short* wb   = (const unsigned short*)(wsf + 66624);
  const unsigned short* BM   = wb;
  const unsigned short* BL   = wb + 512;
  const unsigned short* BRV2 = wb + 2560;
  const unsigned short* BT   = wb + 4608;
  unsigned short* tg = (unsigned short*)(wsf + 66624) + 8704;

  const int tid  = threadIdx.x;
  const int w    = tid >> 6;
  const int lane = tid & 63;
  const int l15  = lane & 15;
  const int q    = lane >> 4;
  const int r0   = w * 16;
  const int n0   = blockIdx.x * 2;
  short* const aw = awB + w * 1152;
  short* const gu = guB + w * 256;

  // ---- stage x,y for both points ----
  {
    const int b = tid >> 2, i = tid & 3;
#pragma unroll
    for (int p = 0; p < 2; ++p) {
      const float* xp = x + ((size_t)b * N_ + n0 + p) * 10;
      const float* yp = y + ((size_t)b * N_ + n0 + p) * 13;
      short* Ar = Axy[p] + b * 40;
      Ar[i]     = (short)f2bf(xp[i]);
      Ar[i + 4] = (short)f2bf(xp[i + 4]);
      short v8 = 0;
      if (i < 2) v8 = (short)f2bf(xp[i + 8]);
      else if (i == 2) v8 = (short)0x3F80;          // xhat "1"
      Ar[i + 8]  = v8;
      Ar[i + 12] = 0;
      const short y0 = (short)f2bf(yp[i]);
      const short y1 = (short)f2bf(yp[i + 4]);
      const short y2 = (short)f2bf(yp[i + 8]);
      short y3 = 0;
      if (i == 0) y3 = (short)f2bf(yp[12]);
      else if (i == 1) y3 = (short)0x3F80;          // yhat "1"
      Ar[16 + i] = y0;  Ar[20 + i] = y1;  Ar[24 + i] = y2;  Ar[28 + i] = y3;
      short* YT = YTb[p];
      YT[i * 72 + b] = y0;  YT[(i + 4) * 72 + b] = y1;
      YT[(i + 8) * 72 + b] = y2;  YT[(i + 12) * 72 + b] = y3;
    }
  }
  __syncthreads();  // S1

  const short8 z8 = {0, 0, 0, 0, 0, 0, 0, 0};
  const f32x4 zero4 = {0.f, 0.f, 0.f, 0.f};
  const short8 bmF = *(const short8*)&BM[l15 * 32 + q * 8];

  // ---- G = xhat M' ; E = G yhat^T  (gu reused across p: wave-local DS) ----
  short8 aAp[2];
  f32x4 E[2][4];
#pragma unroll
  for (int p = 0; p < 2; ++p) {
    aAp[p] = *(const short8*)&Axy[p][(r0 + l15) * 40 + q * 8];
    f32x4 G = MFMA16(aAp[p], bmF, zero4);
#pragma unroll
    for (int j = 0; j < 4; ++j) gu[(q * 4 + j) * 16 + l15] = (short)f2bf(G[j]);
    short8 aG = z8;
    if (q < 2) aG = *(const short8*)&gu[l15 * 16 + q * 8];
#pragma unroll
    for (int f = 0; f < 4; ++f) {
      short8 bk = z8;
      if (q < 2) bk = *(const short8*)&Axy[p][(f * 16 + l15) * 40 + 16 + q * 8];
      E[p][f] = MFMA16(aG, bk, zero4);
    }
  }

  // ---- softmax over e (no max-subtract; |E|<<1, validated R4-R6) ----
#pragma unroll
  for (int p = 0; p < 2; ++p)
#pragma unroll
    for (int j = 0; j < 4; ++j) {
      float s = 0.f;
#pragma unroll
      for (int f = 0; f < 4; ++f) { E[p][f][j] = __expf(E[p][f][j]); s += E[p][f][j]; }
      s += __shfl_xor(s, 1);
      s += __shfl_xor(s, 2);
      s += __shfl_xor(s, 4);
      s += __shfl_xor(s, 8);
      const float inv = 1.0f / s;
#pragma unroll
      for (int f = 0; f < 4; ++f) E[p][f][j] *= inv;   // fold row-softmax scale
    }
  // ---- column sums (L1 renorm) ----
#pragma unroll
  for (int p = 0; p < 2; ++p)
#pragma unroll
    for (int f = 0; f < 4; ++f) {
      float cs = E[p][f][0] + E[p][f][1] + E[p][f][2] + E[p][f][3];
      cs += __shfl_xor(cs, 16);
      cs += __shfl_xor(cs, 32);
      if (lane < 16) scr[p * 256 + w * 64 + f * 16 + l15] = cs;
    }
  __syncthreads();  // S2

  // ---- per point: attn -> U -> yr -> Z -> t  (aw/gu time-muxed) ----
  f32x4 t[2][4];
  float sRed[2][4], ssRed[2][4];
#pragma unroll
  for (int p = 0; p < 2; ++p) {
#pragma unroll
    for (int f = 0; f < 4; ++f) {
      const int col = f * 16 + l15;
      const float* sp = scr + p * 256;
      const float csv = 1.0f / (1e-9f + sp[col] + sp[64 + col] + sp[128 + col] + sp[192 + col]);
#pragma unroll
      for (int j = 0; j < 4; ++j)
        aw[(q * 4 + j) * 72 + col] = (short)f2bf(E[p][f][j] * csv);
    }
    const short8 aA0 = *(const short8*)&aw[l15 * 72 + q * 8];
    const short8 aA1 = *(const short8*)&aw[l15 * 72 + 32 + q * 8];
    f32x4 U = MFMA16(aA0, *(const short8*)&YTb[p][l15 * 72 + q * 8], zero4);
    U = MFMA16(aA1, *(const short8*)&YTb[p][l15 * 72 + 32 + q * 8], U);
#pragma unroll
    for (int j = 0; j < 4; ++j) gu[(q * 4 + j) * 16 + l15] = (short)f2bf(U[j]);
    short8 aU = z8;
    if (q < 2) aU = *(const short8*)&gu[l15 * 16 + q * 8];
#pragma unroll
    for (int f = 0; f < 4; ++f) {
      const int c = f * 16 + l15;
      f32x4 Xf = MFMA16(aAp[p], *(const short8*)&BL[c * 32 + q * 8], zero4);
      f32x4 yr = MFMA16(aU, *(const short8*)&BRV2[c * 32 + q * 8], zero4);
#pragma unroll
      for (int j = 0; j < 4; ++j)
        aw[(q * 4 + j) * 72 + c] = (short)f2bf(Xf[j] - yr[j]);   // Z overlays attn
    }
    const short8 aZ0 = *(const short8*)&aw[l15 * 72 + q * 8];
    const short8 aZ1 = *(const short8*)&aw[l15 * 72 + 32 + q * 8];
#pragma unroll
    for (int f = 0; f < 4; ++f) {
      const int c = f * 16 + l15;
      const float bT = b_t[c];
      t[p][f] = MFMA16(aZ0, *(const short8*)&BT[c * 64 + q * 8], ((f32x4){bT, bT, bT, bT}));
      t[p][f] = MFMA16(aZ1, *(const short8*)&BT[c * 64 + 32 + q * 8], t[p][f]);
      float s = 0.f, ss = 0.f;
#pragma unroll
      for (int j = 0; j < 4; ++j) { s += t[p][f][j]; ss = fmaf(t[p][f][j], t[p][f][j], ss); }
      s  += __shfl_xor(s, 16);  s  += __shfl_xor(s, 32);
      ss += __shfl_xor(ss, 16); ss += __shfl_xor(ss, 32);
      sRed[p][f] = s; ssRed[p][f] = ss;
    }
  }
  __syncthreads();  // S3: colsum reads done; scr reusable
#pragma unroll
  for (int p = 0; p < 2; ++p)
#pragma unroll
    for (int f = 0; f < 4; ++f)
      if (lane < 16) {
        scr[p * 512 + w * 64 + f * 16 + l15]       = sRed[p][f];
        scr[p * 512 + 256 + w * 64 + f * 16 + l15] = ssRed[p][f];
      }
  __syncthreads();  // S4
  if (tid < 128) {
    const int p = tid >> 6, c = tid & 63;
    const float* sp = scr + p * 512;
    const float s  = sp[c] + sp[64 + c] + sp[128 + c] + sp[192 + c];
    const float ss = sp[256 + c] + sp[320 + c] + sp[384 + c] + sp[448 + c];
    float* st = stats + ((n0 + p) & 7) * 128;
    atomicAdd(&st[c], s);
    atomicAdd(&st[64 + c], ss);
  }
  // ---- tg stores LAST: no barrier waits on the scattered-store drain ----
#pragma unroll
  for (int p = 0; p < 2; ++p)
#pragma unroll
    for (int f = 0; f < 4; ++f)
#pragma unroll
      for (int j = 0; j < 4; ++j)
        tg[(size_t)(r0 + q * 4 + j) * (N_ * 64) + (size_t)(n0 + p) * 64 + f * 16 + l15] =
            f2bf(t[p][f][j]);
}

// ---- k3: stats finalize + X recompute + BN/ReLU/residual + max + final ---
__global__ __launch_bounds__(256)
void k3_max(const float* __restrict__ x, const float* __restrict__ W_l,
            const float* __restrict__ b_l, const float* __restrict__ gamma,
            const float* __restrict__ beta, const unsigned short* __restrict__ tg,
            const float* __restrict__ stats, float* __restrict__ pmax,
            unsigned int* __restrict__ cnt, float* __restrict__ out)
{
  __shared__ float mrs[128];
  __shared__ float sm[4][64];
  __shared__ int lastFlag;
  const int b = blockIdx.x >> 4;      // 0..63
  const int chunk = blockIdx.x & 15;  // 512 n's each
  const int tid = threadIdx.x;
  // per-block BN finalize (replaces k2; stats region is L2-hot, 1 KB)
  if (tid < 64) {
    float s = 0.f, ss = 0.f;
    for (int r = 0; r < 8; ++r) { s += stats[r * 128 + tid]; ss += stats[r * 128 + 64 + tid]; }
    const float inv = 1.0f / (float)(B_ * N_);
    const float mu = s * inv;
    const float var = fmaf(ss, inv, -mu * mu);
    mrs[tid] = mu;
    mrs[64 + tid] = rsqrtf(var + 1e-5f);
  }
  __syncthreads();
  const int wv = tid >> 6;
  const int lane = tid & 63;
  const int c0 = (lane & 15) * 4;
  const int nsub = lane >> 4;
  float4 wl4[10];
#pragma unroll
  for (int k = 0; k < 10; ++k) wl4[k] = *(const float4*)&W_l[k * 64 + c0];
  const float4 bl  = *(const float4*)&b_l[c0];
  const float4 g   = *(const float4*)&gamma[c0];
  const float4 be  = *(const float4*)&beta[c0];
  const float4 mu  = *(const float4*)&mrs[c0];
  const float4 rs  = *(const float4*)&mrs[64 + c0];
  float4 grs, bmb;
  grs.x = g.x * rs.x; grs.y = g.y * rs.y; grs.z = g.z * rs.z; grs.w = g.w * rs.w;
  bmb.x = be.x - mu.x * grs.x; bmb.y = be.y - mu.y * grs.y;
  bmb.z = be.z - mu.z * grs.z; bmb.w = be.w - mu.w * grs.w;
  float4 m = {-1e30f, -1e30f, -1e30f, -1e30f};
  const size_t tgb = (size_t)b << 19;           // b * N * 64
  const int n0 = chunk * 512 + wv * 128 + nsub;
#pragma unroll 4
  for (int jj = 0; jj < 32; ++jj) {
    const int n = n0 + jj * 4;
    const uint2 tv = *(const uint2*)&tg[tgb + (size_t)n * 64 + c0];
    const float* xp = x + ((size_t)b * N_ + n) * 10;
    float4 X = bl;
#pragma unroll
    for (int k = 0; k < 10; ++k) {
      const float xk = xp[k];
      X.x = fmaf(xk, wl4[k].x, X.x); X.y = fmaf(xk, wl4[k].y, X.y);
      X.z = fmaf(xk, wl4[k].z, X.z); X.w = fmaf(xk, wl4[k].w, X.w);
    }
    const float t0 = bf2f(tv.x & 0xFFFFu), t1 = bf2f(tv.x >> 16);
    const float t2 = bf2f(tv.y & 0xFFFFu), t3 = bf2f(tv.y >> 16);
    m.x = fmaxf(m.x, X.x + fmaxf(fmaf(t0, grs.x, bmb.x), 0.f));
    m.y = fmaxf(m.y, X.y + fmaxf(fmaf(t1, grs.y, bmb.y), 0.f));
    m.z = fmaxf(m.z, X.z + fmaxf(fmaf(t2, grs.z, bmb.z), 0.f));
    m.w = fmaxf(m.w, X.w + fmaxf(fmaf(t3, grs.w, bmb.w), 0.f));
  }
  m.x = fmaxf(m.x, __shfl_xor(m.x, 16)); m.y = fmaxf(m.y, __shfl_xor(m.y, 16));
  m.z = fmaxf(m.z, __shfl_xor(m.z, 16)); m.w = fmaxf(m.w, __shfl_xor(m.w, 16));
  m.x = fmaxf(m.x, __shfl_xor(m.x, 32)); m.y = fmaxf(m.y, __shfl_xor(m.y, 32));
  m.z = fmaxf(m.z, __shfl_xor(m.z, 32)); m.w = fmaxf(m.w, __shfl_xor(m.w, 32));
  if (lane < 16) *(float4*)&sm[wv][c0] = m;
  __syncthreads();
  if (tid < 64) {
    const float r = fmaxf(fmaxf(sm[0][tid], sm[1][tid]), fmaxf(sm[2][tid], sm[3][tid]));
    pmax[(size_t)blockIdx.x * 64 + tid] = r;
  }
  // last-block-per-b final reduction (replaces k4); G16: fence + device atomics
  __threadfence();
  __syncthreads();
  if (tid == 0) {
    const unsigned old = atomicAdd(&cnt[b], 1u);
    lastFlag = (old == 15u);
  }
  __syncthreads();
  if (lastFlag) {
    __threadfence();
    if (tid < 64) {
      float r = -1e30f;
      for (int ch = 0; ch < 16; ++ch)
        r = fmaxf(r, pmax[(size_t)(b * 16 + ch) * 64 + tid]);
      out[b * 64 + tid] = r;
    }
  }
}

// ---- launcher -------------------------------------------------------------
extern "C" void kernel_launch(void* const* d_in, const int* in_sizes, int n_in,
                              void* d_out, int out_size, void* d_ws, size_t ws_size,
                              hipStream_t stream) {
  const float* x     = (const float*)d_in[0];
  const float* y     = (const float*)d_in[1];
  const float* W_l   = (const float*)d_in[2];
  const float* b_l   = (const float*)d_in[3];
  const float* W_r   = (const float*)d_in[4];
  const float* b_r   = (const float*)d_in[5];
  const float* W_qk  = (const float*)d_in[6];
  const float* W_v   = (const float*)d_in[7];
  const float* b_v   = (const float*)d_in[8];
  const float* W_t   = (const float*)d_in[9];
  const float* b_t   = (const float*)d_in[10];
  const float* gamma = (const float*)d_in[11];
  const float* beta  = (const float*)d_in[12];
  float* out = (float*)d_out;

  float* wsf = (float*)d_ws;
  float* stats = wsf;
  unsigned int* cnt = (unsigned int*)(wsf + 1024);
  float* pmax  = wsf + 1088;
  const unsigned short* tg = (const unsigned short*)(wsf + 66624) + 8704;

  hipLaunchKernelGGL(k0_prep, dim3(4), dim3(256), 0, stream,
                     W_l, b_l, W_r, b_r, W_qk, W_v, b_v, W_t, wsf);
  hipLaunchKernelGGL(k1_attn, dim3(N_ / 2), dim3(256), 0, stream,
                     x, y, wsf, b_t, stats);
  hipLaunchKernelGGL(k3_max, dim3(1024), dim3(256), 0, stream,
                     x, W_l, b_l, gamma, beta, tg, stats, pmax, cnt, out);
}

// Round 8
// 297.536 us; speedup vs baseline: 1.1182x; 1.1182x over previous
//
#include <hip/hip_runtime.h>

#define B_ 64
#define N_ 8192

using short8 = __attribute__((ext_vector_type(8))) short;  // 8 bf16 (4 VGPRs)
using f32x4  = __attribute__((ext_vector_type(4))) float;

#define MFMA16(a, b, c) __builtin_amdgcn_mfma_f32_16x16x32_bf16((a), (b), (c), 0, 0, 0)

// round-half-up bf16: same 2^-9 max-rel-err bound as RNE, 2 VALU instrs
__device__ inline unsigned short f2bf(float f) {
  union { float f; unsigned int u; } v; v.f = f;
  return (unsigned short)((v.u + 0x8000u) >> 16);
}
__device__ inline float bf2f(unsigned int hi16_in_low) {
  union { unsigned int u; float f; } v; v.u = hi16_in_low << 16;
  return v.f;
}

// ws layout (f32 indices):
//   stats [0,1024) | pmax [1088,66624)  (1024 blocks x 64)
//   ushort wb = (ushort*)(wsf+66624):
//     BM   [16 j][32]  @0     (M' = W_lq' W_rk'^T, kk 0..10 = M'[kk][j])
//     BL   [64 c][32]  @512   (kk 0..9 = W_l[kk][c], kk10 = b_l[c])
//     BRV2 [64 c][32]  @2560  (kk 0..12 = (W_r.W_v^T)[kk][c], kk13 = b_rv[c])
//     BT   [64 c][64]  @4608  (W_t)
//     tg   [B][N][64]  @8704  (t, bf16, b-major)
// A-tile k-slots: 0..9 = x, 10 = 1, 11..15 = 0, 16..28 = y, 29 = 1, 30,31 = 0.

// ---- k0: weight prep + zero stats ---------------------------------------
__global__ void k0_prep(const float* __restrict__ W_l, const float* __restrict__ b_l,
                        const float* __restrict__ W_r, const float* __restrict__ b_r,
                        const float* __restrict__ W_qk, const float* __restrict__ W_v,
                        const float* __restrict__ b_v, const float* __restrict__ W_t,
                        float* __restrict__ wsf) {
  const int tid = threadIdx.x;
  unsigned short* wb   = (unsigned short*)(wsf + 66624);
  unsigned short* BM   = wb;
  unsigned short* BL   = wb + 512;
  unsigned short* BRV2 = wb + 2560;
  unsigned short* BT   = wb + 4608;
  if (blockIdx.x == 0) {
    __shared__ float Wlq[11 * 16], Wrk[14 * 16];
    for (int idx = tid; idx < 11 * 16; idx += 256) {
      int i = idx >> 4, d = idx & 15;
      const float* a = (i < 10) ? (W_l + i * 64) : b_l;
      float s = 0.f;
      for (int c = 0; c < 64; ++c) s = fmaf(a[c], W_qk[d * 64 + c], s);
      Wlq[idx] = s;
    }
    for (int idx = tid; idx < 14 * 16; idx += 256) {
      int j = idx >> 4, d = idx & 15;
      const float* a = (j < 13) ? (W_r + j * 64) : b_r;
      float s = 0.f;
      for (int c = 0; c < 64; ++c) s = fmaf(a[c], W_qk[d * 64 + c], s);
      Wrk[idx] = s;
    }
    __syncthreads();
    for (int idx = tid; idx < 512; idx += 256) {
      int j = idx >> 5, kk = idx & 31;
      unsigned short o = 0;
      if (j < 14 && kk < 11) {
        float s = 0.f;
        for (int d = 0; d < 16; ++d) s = fmaf(Wlq[kk * 16 + d], Wrk[j * 16 + d], s);
        o = f2bf(s);
      }
      BM[idx] = o;
    }
  } else if (blockIdx.x == 1) {
    for (int idx = tid; idx < 2048; idx += 256) {
      int c = idx >> 5, kk = idx & 31;
      unsigned short o = 0;
      if (kk < 13) {
        float s = 0.f;
        for (int j = 0; j < 64; ++j) s = fmaf(W_r[kk * 64 + j], W_v[c * 64 + j], s);
        o = f2bf(s);
      } else if (kk == 13) {
        float s = b_v[c];
        for (int j = 0; j < 64; ++j) s = fmaf(b_r[j], W_v[c * 64 + j], s);
        o = f2bf(s);
      }
      BRV2[idx] = o;
    }
  } else if (blockIdx.x == 2) {
    for (int idx = tid; idx < 2048; idx += 256) {
      int c = idx >> 5, kk = idx & 31;
      unsigned short o = 0;
      if (kk < 10) o = f2bf(W_l[kk * 64 + c]);
      else if (kk == 10) o = f2bf(b_l[c]);
      BL[idx] = o;
    }
    for (int i = tid; i < 1024; i += 256) wsf[i] = 0.f;   // stats
  } else {
    for (int i = tid; i < 4096; i += 256) BT[i] = f2bf(W_t[i]);
  }
}

// ---- k1: fused per-point chain, 2 points/block, coalesced t stores -------
__global__ __launch_bounds__(256, 5)
void k1_attn(const float* __restrict__ x, const float* __restrict__ y,
             const float* __restrict__ wsf, const float* __restrict__ b_t,
             float* __restrict__ stats) {
  // LDS: 13056 shorts (26112 B) + 512 f32 (2048 B) = 28160 B -> 5 blocks/CU
  __shared__ __align__(16) short lds[13056];
  __shared__ float scr[512];
  short* const Axy[2] = {lds, lds + 2560};          // [b][k-slot] per point
  short* const YTb[2] = {lds + 5120, lds + 6272};   // yhat^T [j][e] per point
  short* const awB    = lds + 7424;                 // per-wave [16][72], time-muxed
  short* const guB    = lds + 12032;                // per-wave [16][16], time-muxed

  const unsigned short* wb   = (const unsigned short*)(wsf + 66624);
  const unsigned short* BM   = wb;
  const unsigned short* BL   = wb + 512;
  const unsigned short* BRV2 = wb + 2560;
  const unsigned short* BT   = wb + 4608;
  unsigned short* tg = (unsigned short*)(wsf + 66624) + 8704;

  const int tid  = threadIdx.x;
  const int w    = tid >> 6;
  const int lane = tid & 63;
  const int l15  = lane & 15;
  const int q    = lane >> 4;
  const int r0   = w * 16;
  const int n0   = blockIdx.x * 2;
  short* const aw = awB + w * 1152;
  short* const gu = guB + w * 256;

  // ---- stage x,y for both points ----
  {
    const int b = tid >> 2, i = tid & 3;
#pragma unroll
    for (int p = 0; p < 2; ++p) {
      const float* xp = x + ((size_t)b * N_ + n0 + p) * 10;
      const float* yp = y + ((size_t)b * N_ + n0 + p) * 13;
      short* Ar = Axy[p] + b * 40;
      Ar[i]     = (short)f2bf(xp[i]);
      Ar[i + 4] = (short)f2bf(xp[i + 4]);
      short v8 = 0;
      if (i < 2) v8 = (short)f2bf(xp[i + 8]);
      else if (i == 2) v8 = (short)0x3F80;          // xhat "1"
      Ar[i + 8]  = v8;
      Ar[i + 12] = 0;
      const short y0 = (short)f2bf(yp[i]);
      const short y1 = (short)f2bf(yp[i + 4]);
      const short y2 = (short)f2bf(yp[i + 8]);
      short y3 = 0;
      if (i == 0) y3 = (short)f2bf(yp[12]);
      else if (i == 1) y3 = (short)0x3F80;          // yhat "1"
      Ar[16 + i] = y0;  Ar[20 + i] = y1;  Ar[24 + i] = y2;  Ar[28 + i] = y3;
      short* YT = YTb[p];
      YT[i * 72 + b] = y0;  YT[(i + 4) * 72 + b] = y1;
      YT[(i + 8) * 72 + b] = y2;  YT[(i + 12) * 72 + b] = y3;
    }
  }
  __syncthreads();  // S1

  const short8 z8 = {0, 0, 0, 0, 0, 0, 0, 0};
  const f32x4 zero4 = {0.f, 0.f, 0.f, 0.f};
  const short8 bmF = *(const short8*)&BM[l15 * 32 + q * 8];

  // ---- G = xhat M' ; E = G yhat^T  (gu time-muxed across p) ----
  short8 aAp[2];
  f32x4 E[2][4];
#pragma unroll
  for (int p = 0; p < 2; ++p) {
    aAp[p] = *(const short8*)&Axy[p][(r0 + l15) * 40 + q * 8];
    f32x4 G = MFMA16(aAp[p], bmF, zero4);
#pragma unroll
    for (int j = 0; j < 4; ++j) gu[(q * 4 + j) * 16 + l15] = (short)f2bf(G[j]);
    short8 aG = z8;
    if (q < 2) aG = *(const short8*)&gu[l15 * 16 + q * 8];
#pragma unroll
    for (int f = 0; f < 4; ++f) {
      short8 bk = z8;
      if (q < 2) bk = *(const short8*)&Axy[p][(f * 16 + l15) * 40 + 16 + q * 8];
      E[p][f] = MFMA16(aG, bk, zero4);
    }
  }

  // ---- softmax over e (no max-subtract; |E|<<1, validated R4-R7) ----
#pragma unroll
  for (int p = 0; p < 2; ++p)
#pragma unroll
    for (int j = 0; j < 4; ++j) {
      float s = 0.f;
#pragma unroll
      for (int f = 0; f < 4; ++f) { E[p][f][j] = __expf(E[p][f][j]); s += E[p][f][j]; }
      s += __shfl_xor(s, 1);
      s += __shfl_xor(s, 2);
      s += __shfl_xor(s, 4);
      s += __shfl_xor(s, 8);
      const float inv = 1.0f / s;
#pragma unroll
      for (int f = 0; f < 4; ++f) E[p][f][j] *= inv;   // fold row-softmax scale
    }
  // ---- column sums (L1 renorm) ----
#pragma unroll
  for (int p = 0; p < 2; ++p)
#pragma unroll
    for (int f = 0; f < 4; ++f) {
      float cs = E[p][f][0] + E[p][f][1] + E[p][f][2] + E[p][f][3];
      cs += __shfl_xor(cs, 16);
      cs += __shfl_xor(cs, 32);
      if (lane < 16) scr[p * 256 + w * 64 + f * 16 + l15] = cs;
    }
  __syncthreads();  // S2 — the LAST barrier in the kernel

  // ---- per point: attn -> U -> yr -> Z -> t -> stats + coalesced store ----
#pragma unroll
  for (int p = 0; p < 2; ++p) {
#pragma unroll
    for (int f = 0; f < 4; ++f) {
      const int col = f * 16 + l15;
      const float* sp = scr + p * 256;
      const float csv = 1.0f / (1e-9f + sp[col] + sp[64 + col] + sp[128 + col] + sp[192 + col]);
#pragma unroll
      for (int j = 0; j < 4; ++j)
        aw[(q * 4 + j) * 72 + col] = (short)f2bf(E[p][f][j] * csv);
    }
    const short8 aA0 = *(const short8*)&aw[l15 * 72 + q * 8];
    const short8 aA1 = *(const short8*)&aw[l15 * 72 + 32 + q * 8];
    f32x4 U = MFMA16(aA0, *(const short8*)&YTb[p][l15 * 72 + q * 8], zero4);
    U = MFMA16(aA1, *(const short8*)&YTb[p][l15 * 72 + 32 + q * 8], U);
#pragma unroll
    for (int j = 0; j < 4; ++j) gu[(q * 4 + j) * 16 + l15] = (short)f2bf(U[j]);
    short8 aU = z8;
    if (q < 2) aU = *(const short8*)&gu[l15 * 16 + q * 8];
#pragma unroll
    for (int f = 0; f < 4; ++f) {
      const int c = f * 16 + l15;
      f32x4 Xf = MFMA16(aAp[p], *(const short8*)&BL[c * 32 + q * 8], zero4);
      f32x4 yr = MFMA16(aU, *(const short8*)&BRV2[c * 32 + q * 8], zero4);
#pragma unroll
      for (int j = 0; j < 4; ++j)
        aw[(q * 4 + j) * 72 + c] = (short)f2bf(Xf[j] - yr[j]);   // Z overlays attn
    }
    const short8 aZ0 = *(const short8*)&aw[l15 * 72 + q * 8];
    const short8 aZ1 = *(const short8*)&aw[l15 * 72 + 32 + q * 8];
    f32x4 t[4];
    float* st = stats + ((n0 + p) & 7) * 128;
#pragma unroll
    for (int f = 0; f < 4; ++f) {
      const int c = f * 16 + l15;
      const float bT = b_t[c];
      t[f] = MFMA16(aZ0, *(const short8*)&BT[c * 64 + q * 8], ((f32x4){bT, bT, bT, bT}));
      t[f] = MFMA16(aZ1, *(const short8*)&BT[c * 64 + 32 + q * 8], t[f]);
      // stats: wave-level reduce then fire-and-forget atomics (no barriers)
      float s = 0.f, ss = 0.f;
#pragma unroll
      for (int j = 0; j < 4; ++j) { s += t[f][j]; ss = fmaf(t[f][j], t[f][j], ss); }
      s  += __shfl_xor(s, 16);  s  += __shfl_xor(s, 32);
      ss += __shfl_xor(ss, 16); ss += __shfl_xor(ss, 32);
      if (lane < 16) {
        atomicAdd(&st[c], s);
        atomicAdd(&st[64 + c], ss);
      }
    }
    // ---- stage t into aw (stride 68: 2-way bank aliasing = free) ----
#pragma unroll
    for (int f = 0; f < 4; ++f)
#pragma unroll
      for (int j = 0; j < 4; ++j)
        aw[(q * 4 + j) * 68 + f * 16 + l15] = (short)f2bf(t[f][j]);
    // ---- coalesced uint2 stores: each inst writes 4 full 128-B lines ----
    {
      const int c0 = (lane & 15) * 4;
      unsigned short* tp = tg + (size_t)(n0 + p) * 64 + c0;
#pragma unroll
      for (int i = 0; i < 4; ++i) {
        const int rr = i * 4 + (lane >> 4);
        const uint2 v = *(const uint2*)&aw[rr * 68 + c0];
        *(uint2*)&tp[(size_t)(r0 + rr) * (N_ * 64)] = v;
      }
    }
  }
}

// ---- k3: BN finalize (per block) + X recompute + BN/ReLU/residual + max --
__global__ __launch_bounds__(256)
void k3_max(const float* __restrict__ x, const float* __restrict__ W_l,
            const float* __restrict__ b_l, const float* __restrict__ gamma,
            const float* __restrict__ beta, const unsigned short* __restrict__ tg,
            const float* __restrict__ stats, float* __restrict__ pmax)
{
  __shared__ float mrs[128];
  __shared__ float sm[4][64];
  const int b = blockIdx.x >> 4;      // 0..63
  const int chunk = blockIdx.x & 15;  // 512 n's each
  const int tid = threadIdx.x;
  if (tid < 64) {   // replaces k2; stats is 1 KB, L2-hot
    float s = 0.f, ss = 0.f;
    for (int r = 0; r < 8; ++r) { s += stats[r * 128 + tid]; ss += stats[r * 128 + 64 + tid]; }
    const float inv = 1.0f / (float)(B_ * N_);
    const float mu = s * inv;
    const float var = fmaf(ss, inv, -mu * mu);
    mrs[tid] = mu;
    mrs[64 + tid] = rsqrtf(var + 1e-5f);
  }
  __syncthreads();
  const int wv = tid >> 6;
  const int lane = tid & 63;
  const int c0 = (lane & 15) * 4;
  const int nsub = lane >> 4;
  float4 wl4[10];
#pragma unroll
  for (int k = 0; k < 10; ++k) wl4[k] = *(const float4*)&W_l[k * 64 + c0];
  const float4 bl  = *(const float4*)&b_l[c0];
  const float4 g   = *(const float4*)&gamma[c0];
  const float4 be  = *(const float4*)&beta[c0];
  const float4 mu  = *(const float4*)&mrs[c0];
  const float4 rs  = *(const float4*)&mrs[64 + c0];
  float4 grs, bmb;
  grs.x = g.x * rs.x; grs.y = g.y * rs.y; grs.z = g.z * rs.z; grs.w = g.w * rs.w;
  bmb.x = be.x - mu.x * grs.x; bmb.y = be.y - mu.y * grs.y;
  bmb.z = be.z - mu.z * grs.z; bmb.w = be.w - mu.w * grs.w;
  float4 m = {-1e30f, -1e30f, -1e30f, -1e30f};
  const size_t tgb = (size_t)b << 19;           // b * N * 64
  const int n0 = chunk * 512 + wv * 128 + nsub;
#pragma unroll 4
  for (int jj = 0; jj < 32; ++jj) {
    const int n = n0 + jj * 4;
    const uint2 tv = *(const uint2*)&tg[tgb + (size_t)n * 64 + c0];
    const float* xp = x + ((size_t)b * N_ + n) * 10;
    float4 X = bl;
#pragma unroll
    for (int k = 0; k < 10; ++k) {
      const float xk = xp[k];
      X.x = fmaf(xk, wl4[k].x, X.x); X.y = fmaf(xk, wl4[k].y, X.y);
      X.z = fmaf(xk, wl4[k].z, X.z); X.w = fmaf(xk, wl4[k].w, X.w);
    }
    const float t0 = bf2f(tv.x & 0xFFFFu), t1 = bf2f(tv.x >> 16);
    const float t2 = bf2f(tv.y & 0xFFFFu), t3 = bf2f(tv.y >> 16);
    m.x = fmaxf(m.x, X.x + fmaxf(fmaf(t0, grs.x, bmb.x), 0.f));
    m.y = fmaxf(m.y, X.y + fmaxf(fmaf(t1, grs.y, bmb.y), 0.f));
    m.z = fmaxf(m.z, X.z + fmaxf(fmaf(t2, grs.z, bmb.z), 0.f));
    m.w = fmaxf(m.w, X.w + fmaxf(fmaf(t3, grs.w, bmb.w), 0.f));
  }
  m.x = fmaxf(m.x, __shfl_xor(m.x, 16)); m.y = fmaxf(m.y, __shfl_xor(m.y, 16));
  m.z = fmaxf(m.z, __shfl_xor(m.z, 16)); m.w = fmaxf(m.w, __shfl_xor(m.w, 16));
  m.x = fmaxf(m.x, __shfl_xor(m.x, 32)); m.y = fmaxf(m.y, __shfl_xor(m.y, 32));
  m.z = fmaxf(m.z, __shfl_xor(m.z, 32)); m.w = fmaxf(m.w, __shfl_xor(m.w, 32));
  if (lane < 16) *(float4*)&sm[wv][c0] = m;
  __syncthreads();
  if (tid < 64) {
    const float r = fmaxf(fmaxf(sm[0][tid], sm[1][tid]), fmaxf(sm[2][tid], sm[3][tid]));
    pmax[(size_t)blockIdx.x * 64 + tid] = r;
  }
}

// ---- k4: final max over chunks -------------------------------------------
__global__ void k4_final(const float* __restrict__ pmax, float* __restrict__ out) {
  const int b = blockIdx.x, c = threadIdx.x;
  float m = -1e30f;
  for (int ch = 0; ch < 16; ++ch) m = fmaxf(m, pmax[((size_t)b * 16 + ch) * 64 + c]);
  out[b * 64 + c] = m;
}

// ---- launcher -------------------------------------------------------------
extern "C" void kernel_launch(void* const* d_in, const int* in_sizes, int n_in,
                              void* d_out, int out_size, void* d_ws, size_t ws_size,
                              hipStream_t stream) {
  const float* x     = (const float*)d_in[0];
  const float* y     = (const float*)d_in[1];
  const float* W_l   = (const float*)d_in[2];
  const float* b_l   = (const float*)d_in[3];
  const float* W_r   = (const float*)d_in[4];
  const float* b_r   = (const float*)d_in[5];
  const float* W_qk  = (const float*)d_in[6];
  const float* W_v   = (const float*)d_in[7];
  const float* b_v   = (const float*)d_in[8];
  const float* W_t   = (const float*)d_in[9];
  const float* b_t   = (const float*)d_in[10];
  const float* gamma = (const float*)d_in[11];
  const float* beta  = (const float*)d_in[12];
  float* out = (float*)d_out;

  float* wsf = (float*)d_ws;
  float* stats = wsf;
  float* pmax  = wsf + 1088;
  const unsigned short* tg = (const unsigned short*)(wsf + 66624) + 8704;

  hipLaunchKernelGGL(k0_prep, dim3(4), dim3(256), 0, stream,
                     W_l, b_l, W_r, b_r, W_qk, W_v, b_v, W_t, wsf);
  hipLaunchKernelGGL(k1_attn, dim3(N_ / 2), dim3(256), 0, stream,
                     x, y, wsf, b_t, stats);
  hipLaunchKernelGGL(k3_max, dim3(1024), dim3(256), 0, stream,
                     x, W_l, b_l, gamma, beta, tg, stats, pmax);
  hipLaunchKernelGGL(k4_final, dim3(64), dim3(64), 0, stream, pmax, out);
}

// Round 9
// 242.164 us; speedup vs baseline: 1.3739x; 1.2287x over previous
//
#include <hip/hip_runtime.h>

#define B_ 64
#define N_ 8192

using short8 = __attribute__((ext_vector_type(8))) short;  // 8 bf16 (4 VGPRs)
using f32x4  = __attribute__((ext_vector_type(4))) float;

#define MFMA16(a, b, c) __builtin_amdgcn_mfma_f32_16x16x32_bf16((a), (b), (c), 0, 0, 0)

// round-half-up bf16: same 2^-9 max-rel-err bound as RNE, 2 VALU instrs
__device__ inline unsigned short f2bf(float f) {
  union { float f; unsigned int u; } v; v.f = f;
  return (unsigned short)((v.u + 0x8000u) >> 16);
}
__device__ inline float bf2f(unsigned int hi16_in_low) {
  union { unsigned int u; float f; } v; v.u = hi16_in_low << 16;
  return v.f;
}

// ws layout (f32 indices):
//   stats [0,2048)  (16 copies x 128, atomic-spread) | pmax [2048,67584)
//   ushort wb = (ushort*)(wsf+69632):
//     BM   [16 j][32]  @0     (M' = W_lq' W_rk'^T, kk 0..10 = M'[kk][j])
//     BL   [64 c][32]  @512   (kk 0..9 = W_l[kk][c], kk10 = b_l[c])
//     BRV2 [64 c][32]  @2560  (kk 0..12 = (W_r.W_v^T)[kk][c], kk13 = b_rv[c])
//     BT   [64 c][64]  @4608  (W_t)
//     tg   [B][N][64]  @8704  (t, bf16, b-major)
// A-tile k-slots: 0..9 = x, 10 = 1, 11..15 = 0, 16..28 = y, 29 = 1, 30,31 = 0.

// ---- k0: weight prep + zero stats ---------------------------------------
__global__ void k0_prep(const float* __restrict__ W_l, const float* __restrict__ b_l,
                        const float* __restrict__ W_r, const float* __restrict__ b_r,
                        const float* __restrict__ W_qk, const float* __restrict__ W_v,
                        const float* __restrict__ b_v, const float* __restrict__ W_t,
                        float* __restrict__ wsf) {
  const int tid = threadIdx.x;
  unsigned short* wb   = (unsigned short*)(wsf + 69632);
  unsigned short* BM   = wb;
  unsigned short* BL   = wb + 512;
  unsigned short* BRV2 = wb + 2560;
  unsigned short* BT   = wb + 4608;
  if (blockIdx.x == 0) {
    __shared__ float Wlq[11 * 16], Wrk[14 * 16];
    for (int idx = tid; idx < 11 * 16; idx += 256) {
      int i = idx >> 4, d = idx & 15;
      const float* a = (i < 10) ? (W_l + i * 64) : b_l;
      float s = 0.f;
      for (int c = 0; c < 64; ++c) s = fmaf(a[c], W_qk[d * 64 + c], s);
      Wlq[idx] = s;
    }
    for (int idx = tid; idx < 14 * 16; idx += 256) {
      int j = idx >> 4, d = idx & 15;
      const float* a = (j < 13) ? (W_r + j * 64) : b_r;
      float s = 0.f;
      for (int c = 0; c < 64; ++c) s = fmaf(a[c], W_qk[d * 64 + c], s);
      Wrk[idx] = s;
    }
    __syncthreads();
    for (int idx = tid; idx < 512; idx += 256) {
      int j = idx >> 5, kk = idx & 31;
      unsigned short o = 0;
      if (j < 14 && kk < 11) {
        float s = 0.f;
        for (int d = 0; d < 16; ++d) s = fmaf(Wlq[kk * 16 + d], Wrk[j * 16 + d], s);
        o = f2bf(s);
      }
      BM[idx] = o;
    }
  } else if (blockIdx.x == 1) {
    for (int idx = tid; idx < 2048; idx += 256) {
      int c = idx >> 5, kk = idx & 31;
      unsigned short o = 0;
      if (kk < 13) {
        float s = 0.f;
        for (int j = 0; j < 64; ++j) s = fmaf(W_r[kk * 64 + j], W_v[c * 64 + j], s);
        o = f2bf(s);
      } else if (kk == 13) {
        float s = b_v[c];
        for (int j = 0; j < 64; ++j) s = fmaf(b_r[j], W_v[c * 64 + j], s);
        o = f2bf(s);
      }
      BRV2[idx] = o;
    }
  } else if (blockIdx.x == 2) {
    for (int idx = tid; idx < 2048; idx += 256) {
      int c = idx >> 5, kk = idx & 31;
      unsigned short o = 0;
      if (kk < 10) o = f2bf(W_l[kk * 64 + c]);
      else if (kk == 10) o = f2bf(b_l[c]);
      BL[idx] = o;
    }
    for (int i = tid; i < 2048; i += 256) wsf[i] = 0.f;   // stats (16 copies)
  } else {
    for (int i = tid; i < 4096; i += 256) BT[i] = f2bf(W_t[i]);
  }
}

// ---- k1: fused per-point chain, 2 points/block ---------------------------
// Tail order: block-reduced stats -> atomics (tid<128) -> staged coalesced
// stores LAST (no barrier ever waits on a global-store drain).
__global__ __launch_bounds__(256, 5)
void k1_attn(const float* __restrict__ x, const float* __restrict__ y,
             const float* __restrict__ wsf, const float* __restrict__ b_t,
             float* __restrict__ stats) {
  // LDS: 13056 shorts (26112 B) + 1024 f32 (4096 B) = 30208 B -> 5 blocks/CU
  __shared__ __align__(16) short lds[13056];
  __shared__ float scr[1024];
  short* const Axy[2] = {lds, lds + 2560};          // [b][k-slot] per point
  short* const YTb[2] = {lds + 5120, lds + 6272};   // yhat^T [j][e] per point
  short* const awB    = lds + 7424;                 // per-wave [16][72], time-muxed
  short* const guB    = lds + 12032;                // per-wave [16][16], time-muxed

  const unsigned short* wb   = (const unsigned short*)(wsf + 69632);
  const unsigned short* BM   = wb;
  const unsigned short* BL   = wb + 512;
  const unsigned short* BRV2 = wb + 2560;
  const unsigned short* BT   = wb + 4608;
  unsigned short* tg = (unsigned short*)(wsf + 69632) + 8704;

  const int tid  = threadIdx.x;
  const int w    = tid >> 6;
  const int lane = tid & 63;
  const int l15  = lane & 15;
  const int q    = lane >> 4;
  const int r0   = w * 16;
  const int n0   = blockIdx.x * 2;
  short* const aw = awB + w * 1152;
  short* const gu = guB + w * 256;

  // ---- stage x,y for both points ----
  {
    const int b = tid >> 2, i = tid & 3;
#pragma unroll
    for (int p = 0; p < 2; ++p) {
      const float* xp = x + ((size_t)b * N_ + n0 + p) * 10;
      const float* yp = y + ((size_t)b * N_ + n0 + p) * 13;
      short* Ar = Axy[p] + b * 40;
      Ar[i]     = (short)f2bf(xp[i]);
      Ar[i + 4] = (short)f2bf(xp[i + 4]);
      short v8 = 0;
      if (i < 2) v8 = (short)f2bf(xp[i + 8]);
      else if (i == 2) v8 = (short)0x3F80;          // xhat "1"
      Ar[i + 8]  = v8;
      Ar[i + 12] = 0;
      const short y0 = (short)f2bf(yp[i]);
      const short y1 = (short)f2bf(yp[i + 4]);
      const short y2 = (short)f2bf(yp[i + 8]);
      short y3 = 0;
      if (i == 0) y3 = (short)f2bf(yp[12]);
      else if (i == 1) y3 = (short)0x3F80;          // yhat "1"
      Ar[16 + i] = y0;  Ar[20 + i] = y1;  Ar[24 + i] = y2;  Ar[28 + i] = y3;
      short* YT = YTb[p];
      YT[i * 72 + b] = y0;  YT[(i + 4) * 72 + b] = y1;
      YT[(i + 8) * 72 + b] = y2;  YT[(i + 12) * 72 + b] = y3;
    }
  }
  __syncthreads();  // S1

  const short8 z8 = {0, 0, 0, 0, 0, 0, 0, 0};
  const f32x4 zero4 = {0.f, 0.f, 0.f, 0.f};
  const short8 bmF = *(const short8*)&BM[l15 * 32 + q * 8];

  // ---- G = xhat M' ; E = G yhat^T  (gu time-muxed across p) ----
  short8 aAp[2];
  f32x4 E[2][4];
#pragma unroll
  for (int p = 0; p < 2; ++p) {
    aAp[p] = *(const short8*)&Axy[p][(r0 + l15) * 40 + q * 8];
    f32x4 G = MFMA16(aAp[p], bmF, zero4);
#pragma unroll
    for (int j = 0; j < 4; ++j) gu[(q * 4 + j) * 16 + l15] = (short)f2bf(G[j]);
    short8 aG = z8;
    if (q < 2) aG = *(const short8*)&gu[l15 * 16 + q * 8];
#pragma unroll
    for (int f = 0; f < 4; ++f) {
      short8 bk = z8;
      if (q < 2) bk = *(const short8*)&Axy[p][(f * 16 + l15) * 40 + 16 + q * 8];
      E[p][f] = MFMA16(aG, bk, zero4);
    }
  }

  // ---- softmax over e (no max-subtract; |E|<<1, validated R4-R8) ----
#pragma unroll
  for (int p = 0; p < 2; ++p)
#pragma unroll
    for (int j = 0; j < 4; ++j) {
      float s = 0.f;
#pragma unroll
      for (int f = 0; f < 4; ++f) { E[p][f][j] = __expf(E[p][f][j]); s += E[p][f][j]; }
      s += __shfl_xor(s, 1);
      s += __shfl_xor(s, 2);
      s += __shfl_xor(s, 4);
      s += __shfl_xor(s, 8);
      const float inv = 1.0f / s;
#pragma unroll
      for (int f = 0; f < 4; ++f) E[p][f][j] *= inv;   // fold row-softmax scale
    }
  // ---- column sums (L1 renorm) ----
#pragma unroll
  for (int p = 0; p < 2; ++p)
#pragma unroll
    for (int f = 0; f < 4; ++f) {
      float cs = E[p][f][0] + E[p][f][1] + E[p][f][2] + E[p][f][3];
      cs += __shfl_xor(cs, 16);
      cs += __shfl_xor(cs, 32);
      if (lane < 16) scr[p * 256 + w * 64 + f * 16 + l15] = cs;
    }
  __syncthreads();  // S2

  // ---- per point: attn -> U -> yr -> Z -> t (registers) ----
  f32x4 t[2][4];
  float sRed[2][4], ssRed[2][4];
#pragma unroll
  for (int p = 0; p < 2; ++p) {
#pragma unroll
    for (int f = 0; f < 4; ++f) {
      const int col = f * 16 + l15;
      const float* sp = scr + p * 256;
      const float csv = 1.0f / (1e-9f + sp[col] + sp[64 + col] + sp[128 + col] + sp[192 + col]);
#pragma unroll
      for (int j = 0; j < 4; ++j)
        aw[(q * 4 + j) * 72 + col] = (short)f2bf(E[p][f][j] * csv);
    }
    const short8 aA0 = *(const short8*)&aw[l15 * 72 + q * 8];
    const short8 aA1 = *(const short8*)&aw[l15 * 72 + 32 + q * 8];
    f32x4 U = MFMA16(aA0, *(const short8*)&YTb[p][l15 * 72 + q * 8], zero4);
    U = MFMA16(aA1, *(const short8*)&YTb[p][l15 * 72 + 32 + q * 8], U);
#pragma unroll
    for (int j = 0; j < 4; ++j) gu[(q * 4 + j) * 16 + l15] = (short)f2bf(U[j]);
    short8 aU = z8;
    if (q < 2) aU = *(const short8*)&gu[l15 * 16 + q * 8];
#pragma unroll
    for (int f = 0; f < 4; ++f) {
      const int c = f * 16 + l15;
      f32x4 Xf = MFMA16(aAp[p], *(const short8*)&BL[c * 32 + q * 8], zero4);
      f32x4 yr = MFMA16(aU, *(const short8*)&BRV2[c * 32 + q * 8], zero4);
#pragma unroll
      for (int j = 0; j < 4; ++j)
        aw[(q * 4 + j) * 72 + c] = (short)f2bf(Xf[j] - yr[j]);   // Z overlays attn
    }
    const short8 aZ0 = *(const short8*)&aw[l15 * 72 + q * 8];
    const short8 aZ1 = *(const short8*)&aw[l15 * 72 + 32 + q * 8];
#pragma unroll
    for (int f = 0; f < 4; ++f) {
      const int c = f * 16 + l15;
      const float bT = b_t[c];
      t[p][f] = MFMA16(aZ0, *(const short8*)&BT[c * 64 + q * 8], ((f32x4){bT, bT, bT, bT}));
      t[p][f] = MFMA16(aZ1, *(const short8*)&BT[c * 64 + 32 + q * 8], t[p][f]);
      float s = 0.f, ss = 0.f;
#pragma unroll
      for (int j = 0; j < 4; ++j) { s += t[p][f][j]; ss = fmaf(t[p][f][j], t[p][f][j], ss); }
      s  += __shfl_xor(s, 16);  s  += __shfl_xor(s, 32);
      ss += __shfl_xor(ss, 16); ss += __shfl_xor(ss, 32);
      sRed[p][f] = s; ssRed[p][f] = ss;
    }
  }
  __syncthreads();  // S3: colsum reads done; scr reusable
#pragma unroll
  for (int p = 0; p < 2; ++p)
#pragma unroll
    for (int f = 0; f < 4; ++f)
      if (lane < 16) {
        scr[p * 512 + w * 64 + f * 16 + l15]       = sRed[p][f];
        scr[p * 512 + 256 + w * 64 + f * 16 + l15] = ssRed[p][f];
      }
  __syncthreads();  // S4 — LAST barrier; no global stores issued yet
  if (tid < 128) {
    const int p = tid >> 6, c = tid & 63;
    const float* sp = scr + p * 512;
    const float s  = sp[c] + sp[64 + c] + sp[128 + c] + sp[192 + c];
    const float ss = sp[256 + c] + sp[320 + c] + sp[384 + c] + sp[448 + c];
    float* st = stats + ((n0 + p) & 15) * 128;   // 16-copy spread (64 lines)
    atomicAdd(&st[c], s);
    atomicAdd(&st[64 + c], ss);
  }
  // ---- staged coalesced stores, AFTER all barriers ----
#pragma unroll
  for (int p = 0; p < 2; ++p) {
    // stage t into aw (stride 68: 2-way bank aliasing = free; wave-local,
    // DS in-order => no barrier needed, also safe across p reuse)
#pragma unroll
    for (int f = 0; f < 4; ++f)
#pragma unroll
      for (int j = 0; j < 4; ++j)
        aw[(q * 4 + j) * 68 + f * 16 + l15] = (short)f2bf(t[p][f][j]);
    const int c0 = (lane & 15) * 4;
    unsigned short* tp = tg + (size_t)(n0 + p) * 64 + c0;
#pragma unroll
    for (int i = 0; i < 4; ++i) {
      const int rr = i * 4 + (lane >> 4);
      const uint2 v = *(const uint2*)&aw[rr * 68 + c0];
      *(uint2*)&tp[(size_t)(r0 + rr) * (N_ * 64)] = v;   // 4 full 128-B lines/inst
    }
  }
}

// ---- k3: BN finalize (per block) + X recompute + BN/ReLU/residual + max --
__global__ __launch_bounds__(256)
void k3_max(const float* __restrict__ x, const float* __restrict__ W_l,
            const float* __restrict__ b_l, const float* __restrict__ gamma,
            const float* __restrict__ beta, const unsigned short* __restrict__ tg,
            const float* __restrict__ stats, float* __restrict__ pmax)
{
  __shared__ float mrs[128];
  __shared__ float sm[4][64];
  const int b = blockIdx.x >> 4;      // 0..63
  const int chunk = blockIdx.x & 15;  // 512 n's each
  const int tid = threadIdx.x;
  if (tid < 64) {   // replaces k2; stats is 8 KB, L2-hot
    float s = 0.f, ss = 0.f;
    for (int r = 0; r < 16; ++r) { s += stats[r * 128 + tid]; ss += stats[r * 128 + 64 + tid]; }
    const float inv = 1.0f / (float)(B_ * N_);
    const float mu = s * inv;
    const float var = fmaf(ss, inv, -mu * mu);
    mrs[tid] = mu;
    mrs[64 + tid] = rsqrtf(var + 1e-5f);
  }
  __syncthreads();
  const int wv = tid >> 6;
  const int lane = tid & 63;
  const int c0 = (lane & 15) * 4;
  const int nsub = lane >> 4;
  float4 wl4[10];
#pragma unroll
  for (int k = 0; k < 10; ++k) wl4[k] = *(const float4*)&W_l[k * 64 + c0];
  const float4 bl  = *(const float4*)&b_l[c0];
  const float4 g   = *(const float4*)&gamma[c0];
  const float4 be  = *(const float4*)&beta[c0];
  const float4 mu  = *(const float4*)&mrs[c0];
  const float4 rs  = *(const float4*)&mrs[64 + c0];
  float4 grs, bmb;
  grs.x = g.x * rs.x; grs.y = g.y * rs.y; grs.z = g.z * rs.z; grs.w = g.w * rs.w;
  bmb.x = be.x - mu.x * grs.x; bmb.y = be.y - mu.y * grs.y;
  bmb.z = be.z - mu.z * grs.z; bmb.w = be.w - mu.w * grs.w;
  float4 m = {-1e30f, -1e30f, -1e30f, -1e30f};
  const size_t tgb = (size_t)b << 19;           // b * N * 64
  const int n0 = chunk * 512 + wv * 128 + nsub;
#pragma unroll 4
  for (int jj = 0; jj < 32; ++jj) {
    const int n = n0 + jj * 4;
    const uint2 tv = *(const uint2*)&tg[tgb + (size_t)n * 64 + c0];
    const float* xp = x + ((size_t)b * N_ + n) * 10;
    float4 X = bl;
#pragma unroll
    for (int k = 0; k < 10; ++k) {
      const float xk = xp[k];
      X.x = fmaf(xk, wl4[k].x, X.x); X.y = fmaf(xk, wl4[k].y, X.y);
      X.z = fmaf(xk, wl4[k].z, X.z); X.w = fmaf(xk, wl4[k].w, X.w);
    }
    const float t0 = bf2f(tv.x & 0xFFFFu), t1 = bf2f(tv.x >> 16);
    const float t2 = bf2f(tv.y & 0xFFFFu), t3 = bf2f(tv.y >> 16);
    m.x = fmaxf(m.x, X.x + fmaxf(fmaf(t0, grs.x, bmb.x), 0.f));
    m.y = fmaxf(m.y, X.y + fmaxf(fmaf(t1, grs.y, bmb.y), 0.f));
    m.z = fmaxf(m.z, X.z + fmaxf(fmaf(t2, grs.z, bmb.z), 0.f));
    m.w = fmaxf(m.w, X.w + fmaxf(fmaf(t3, grs.w, bmb.w), 0.f));
  }
  m.x = fmaxf(m.x, __shfl_xor(m.x, 16)); m.y = fmaxf(m.y, __shfl_xor(m.y, 16));
  m.z = fmaxf(m.z, __shfl_xor(m.z, 16)); m.w = fmaxf(m.w, __shfl_xor(m.w, 16));
  m.x = fmaxf(m.x, __shfl_xor(m.x, 32)); m.y = fmaxf(m.y, __shfl_xor(m.y, 32));
  m.z = fmaxf(m.z, __shfl_xor(m.z, 32)); m.w = fmaxf(m.w, __shfl_xor(m.w, 32));
  if (lane < 16) *(float4*)&sm[wv][c0] = m;
  __syncthreads();
  if (tid < 64) {
    const float r = fmaxf(fmaxf(sm[0][tid], sm[1][tid]), fmaxf(sm[2][tid], sm[3][tid]));
    pmax[(size_t)blockIdx.x * 64 + tid] = r;
  }
}

// ---- k4: final max over chunks -------------------------------------------
__global__ void k4_final(const float* __restrict__ pmax, float* __restrict__ out) {
  const int b = blockIdx.x, c = threadIdx.x;
  float m = -1e30f;
  for (int ch = 0; ch < 16; ++ch) m = fmaxf(m, pmax[((size_t)b * 16 + ch) * 64 + c]);
  out[b * 64 + c] = m;
}

// ---- launcher -------------------------------------------------------------
extern "C" void kernel_launch(void* const* d_in, const int* in_sizes, int n_in,
                              void* d_out, int out_size, void* d_ws, size_t ws_size,
                              hipStream_t stream) {
  const float* x     = (const float*)d_in[0];
  const float* y     = (const float*)d_in[1];
  const float* W_l   = (const float*)d_in[2];
  const float* b_l   = (const float*)d_in[3];
  const float* W_r   = (const float*)d_in[4];
  const float* b_r   = (const float*)d_in[5];
  const float* W_qk  = (const float*)d_in[6];
  const float* W_v   = (const float*)d_in[7];
  const float* b_v   = (const float*)d_in[8];
  const float* W_t   = (const float*)d_in[9];
  const float* b_t   = (const float*)d_in[10];
  const float* gamma = (const float*)d_in[11];
  const float* beta  = (const float*)d_in[12];
  float* out = (float*)d_out;

  float* wsf = (float*)d_ws;
  float* stats = wsf;
  float* pmax  = wsf + 2048;
  const unsigned short* tg = (const unsigned short*)(wsf + 69632) + 8704;

  hipLaunchKernelGGL(k0_prep, dim3(4), dim3(256), 0, stream,
                     W_l, b_l, W_r, b_r, W_qk, W_v, b_v, W_t, wsf);
  hipLaunchKernelGGL(k1_attn, dim3(N_ / 2), dim3(256), 0, stream,
                     x, y, wsf, b_t, stats);
  hipLaunchKernelGGL(k3_max, dim3(1024), dim3(256), 0, stream,
                     x, W_l, b_l, gamma, beta, tg, stats, pmax);
  hipLaunchKernelGGL(k4_final, dim3(64), dim3(64), 0, stream, pmax, out);
}